// Round 5
// baseline (152.988 us; speedup 1.0000x reference)
//
#include <hip/hip_runtime.h>
#include <stdint.h>

#define N_NODES 2048
#define N_BATCH 4
#define ROWS_PER_BLOCK 8
#define THREADS 512            // 8 waves, one row per wave
#define TJ 256                 // j-tile per stage buffer (1 KB/array/wave)
#define NTILES (N_NODES / TJ)  // 8 tiles per row

__device__ __forceinline__ uint32_t bf16rn(float x) {
    uint32_t u = __float_as_uint(x);
    u += 0x7fffu + ((u >> 16) & 1u);
    return u >> 16;
}

// async global->LDS DMA, 16 B per lane. LDS dest is WAVE-UNIFORM base
// (HW adds lane*16); global src is per-lane.
__device__ __forceinline__ void gload_lds16(const float* g, float* l) {
    __builtin_amdgcn_global_load_lds(
        (const __attribute__((address_space(1))) void*)(g),
        (__attribute__((address_space(3))) void*)(l),
        16, 0, 0);
}

#define WAITV(N)  asm volatile("s_waitcnt vmcnt(" #N ")" ::: "memory")
#define WAITLGKM0 asm volatile("s_waitcnt lgkmcnt(0)" ::: "memory")

// R0/R2/R4 all pinned at ~2.7 TB/s delivered: register-based MLP can't hold
// enough in-flight bytes at usable occupancy (R4: compiler sank the 16x
// float4 prefetch rather than allocate 64 VGPRs for it). This version moves
// the in-flight data OUT of VGPRs: per-wave double-buffered global_load_lds
// DMA with counted vmcnt(2) waits and NO barrier in the hot loop (each wave
// reads only its own staging buffers). LDS = 32 KB table + 32 KB stage
// = 64 KB -> 2 blocks/CU, 16 waves/CU, ~32-48 KB in flight per CU.
__global__ __launch_bounds__(THREADS, 4) void kuramoto_kernel(
    const float* __restrict__ theta,
    const float* __restrict__ gamma,
    const float* __restrict__ W,
    const float* __restrict__ alpha,
    float* __restrict__ out)
{
    // SoA by d: tbl[d][j] = (bf16(cos th_jd)<<16) | bf16(sin th_jd)
    __shared__ uint32_t tbl[4][N_NODES];                  // 32 KB
    // per-wave staging: [wave][buf][arr: 0=W 1=alpha][j-in-tile]
    __shared__ float stg[ROWS_PER_BLOCK][2][2][TJ];       // 32 KB

    const int tid  = threadIdx.x;
    const int lane = tid & 63;
    const int wave = tid >> 6;
    const int b    = blockIdx.x >> 8;                      // 256 blocks per batch
    const int i    = ((blockIdx.x & 255) * ROWS_PER_BLOCK) + wave;

    const size_t rowbase = ((size_t)b * N_NODES + i) * N_NODES;
    const float* Wr = W + rowbase;
    const float* Ar = alpha + rowbase;

    // ---- Prologue: DMA tiles 0,1 into both buffers. Issued before phase 1;
    // the __syncthreads() vmcnt-drain retires them under the table build.
    gload_lds16(Wr + 0      + lane * 4, &stg[wave][0][0][0]);
    gload_lds16(Ar + 0      + lane * 4, &stg[wave][0][1][0]);
    gload_lds16(Wr + TJ     + lane * 4, &stg[wave][1][0][0]);
    gload_lds16(Ar + TJ     + lane * 4, &stg[wave][1][1][0]);

    // ---- Phase 1: stage sin/cos(theta[b,:,:]) into LDS, bf16-packed ----
    const float* thb = theta + (size_t)b * (N_NODES * 4);
    #pragma unroll
    for (int g = 0; g < N_NODES / THREADS; ++g) {
        const int j = tid + g * THREADS;
        const float4 u = *(const float4*)(thb + (size_t)j * 4);  // coalesced
        const float th[4] = {u.x, u.y, u.z, u.w};
        #pragma unroll
        for (int d = 0; d < 4; ++d) {
            float s, c;
            __sincosf(th[d], &s, &c);
            tbl[d][j] = (bf16rn(c) << 16) | bf16rn(s);  // stride 4B: conflict-free
        }
    }
    __syncthreads();   // drains vmcnt(0): tiles 0,1 are resident past here

    // ---- Phase 2: per-wave DMA pipeline, counted waits, no barriers ----
    //   im_d = sum_j (A*s_jd - B*c_jd),  re_d = sum_j (A*c_jd + B*s_jd)
    //   A = W*cos(alpha), B = W*sin(alpha)
    float re[4] = {0.f, 0.f, 0.f, 0.f};
    float im[4] = {0.f, 0.f, 0.f, 0.f};

    #pragma unroll
    for (int k = 0; k < NTILES; ++k) {
        // tile k ready when <=2 loads (tile k+1) outstanding; never drain-0
        // until the last iteration.
        if (k < NTILES - 1) { WAITV(2); } else { WAITV(0); }
        __builtin_amdgcn_sched_barrier(0);

        const int buf = k & 1;
        const float4 wv = *(const float4*)&stg[wave][buf][0][lane * 4];  // ds_read_b128
        const float4 av = *(const float4*)&stg[wave][buf][1][lane * 4];
        WAITLGKM0;                       // data in regs before buffer reuse
        __builtin_amdgcn_sched_barrier(0);

        if (k + 2 < NTILES) {            // refill the buffer we just read
            const int jn = (k + 2) * TJ + lane * 4;
            gload_lds16(Wr + jn, &stg[wave][buf][0][0]);
            gload_lds16(Ar + jn, &stg[wave][buf][1][0]);
        }

        const int j0 = k * TJ + lane * 4;
        const float wq[4] = {wv.x, wv.y, wv.z, wv.w};
        const float aq[4] = {av.x, av.y, av.z, av.w};
        float A[4], Bq[4];
        #pragma unroll
        for (int q = 0; q < 4; ++q) {
            float sa, ca;
            __sincosf(aq[q], &sa, &ca);
            A[q]  = wq[q] * ca;
            Bq[q] = wq[q] * sa;
        }
        #pragma unroll
        for (int d = 0; d < 4; ++d) {
            const uint4 t = *(const uint4*)&tbl[d][j0];  // one tile live at a time
            const uint32_t tu[4] = {t.x, t.y, t.z, t.w};
            #pragma unroll
            for (int q = 0; q < 4; ++q) {
                const float s = __uint_as_float(tu[q] << 16);
                const float c = __uint_as_float(tu[q] & 0xffff0000u);
                re[d] = fmaf(A[q],   c, re[d]);
                re[d] = fmaf(Bq[q],  s, re[d]);
                im[d] = fmaf(A[q],   s, im[d]);
                im[d] = fmaf(-Bq[q], c, im[d]);
            }
        }
    }

    // ---- Reduction: 6-stage butterfly over 64 lanes, 8 accumulators ----
    #pragma unroll
    for (int stage = 1; stage < 64; stage <<= 1) {
        #pragma unroll
        for (int d = 0; d < 4; ++d) {
            re[d] += __shfl_xor(re[d], stage, 64);
            im[d] += __shfl_xor(im[d], stage, 64);
        }
    }

    if (lane == 0) {
        const size_t obase = ((size_t)b * N_NODES + i) * 4;
        const float4 th4 = *(const float4*)(thb + (size_t)i * 4);
        const float4 g4  = *(const float4*)(gamma + obase);
        const float thd[4] = {th4.x, th4.y, th4.z, th4.w};
        const float gd[4]  = {g4.x, g4.y, g4.z, g4.w};
        float t[4];
        float s2 = 0.0f;
        #pragma unroll
        for (int d = 0; d < 4; ++d) {
            float s_i, c_i;
            __sincosf(thd[d], &s_i, &c_i);
            const float coup = (c_i * im[d] - s_i * re[d]) * (1.0f / (float)N_NODES);
            t[d] = gd[d] + coup;   // theta + (gamma-theta) + coupling  (DT=ATTR=1)
            s2 = fmaf(t[d], t[d], s2);
        }
        const float inv = 1.0f / fmaxf(sqrtf(s2), 1e-6f);
        *(float4*)(out + obase) = make_float4(t[0]*inv, t[1]*inv, t[2]*inv, t[3]*inv);
    }
}

extern "C" void kernel_launch(void* const* d_in, const int* in_sizes, int n_in,
                              void* d_out, int out_size, void* d_ws, size_t ws_size,
                              hipStream_t stream) {
    const float* theta = (const float*)d_in[0];
    const float* gamma = (const float*)d_in[1];
    const float* W     = (const float*)d_in[2];
    const float* alpha = (const float*)d_in[3];
    float* out = (float*)d_out;

    const int grid = (N_BATCH * N_NODES) / ROWS_PER_BLOCK;  // 1024 blocks = 2/CU resident
    hipLaunchKernelGGL(kuramoto_kernel, dim3(grid), dim3(THREADS), 0, stream,
                       theta, gamma, W, alpha, out);
}